// Round 20
// baseline (465.916 us; speedup 1.0000x reference)
//
#include <hip/hip_runtime.h>
#include <math.h>

#define DEPTH 17
#define NNODES ((1 << DEPTH) - 1)
#define WXN 4096  // nodes < WXN get precomputed wx (levels k <= 11)

typedef _Float16 f16x8 __attribute__((ext_vector_type(8)));
typedef float f32x4 __attribute__((ext_vector_type(4)));

// [5/4] Pade tanh, clamped at |x|<=3.4: max err ~1.3e-3 (loose 1.7e-2 tol)
__device__ __forceinline__ float tanhP(float x) {
  float t = fminf(fmaxf(x, -3.4f), 3.4f);
  float s = t * t;
  float num = t * (945.0f + s * (105.0f + s));
  float den = 945.0f + s * (420.0f + 15.0f * s);
  return num * __builtin_amdgcn_rcpf(den);
}
__device__ __forceinline__ float sigP(float x) {
  return 0.5f + 0.5f * tanhP(0.5f * x);
}
__device__ __forceinline__ f16x8 pack8(const float4& a, const float4& b) {
  f16x8 r;
  r[0] = (_Float16)a.x; r[1] = (_Float16)a.y;
  r[2] = (_Float16)a.z; r[3] = (_Float16)a.w;
  r[4] = (_Float16)b.x; r[5] = (_Float16)b.y;
  r[6] = (_Float16)b.z; r[7] = (_Float16)b.w;
  return r;
}

// Lane-order-packed weights: for each (nb, w, g, cb) a 16x32 f16 tile stored
// so lane (q*16+l15) holds elems l15*32 + q*8 .. +7 -> one wave B-fragment =
// contiguous 1 KB, coalesced, L2-resident (1.97 MB total).
__global__ __launch_bounds__(256) void build_wb2(
    _Float16* __restrict__ Wb2, const float* __restrict__ W_iou,
    const float* __restrict__ U_iou, const float* __restrict__ U_f_w) {
  int idx = blockIdx.x * 256 + threadIdx.x;  // grid covers 1280*768 exactly
  int within = idx & 511;                    // l15*32 + kk
  int blk = idx >> 9;                        // ((nb*4+w)*5 + g)*24 + cb
  int l15 = within >> 5;
  int kk = within & 31;
  int cb = blk % 24;
  int t = blk / 24;
  int g = t % 5;
  int t2 = t / 5;
  int w = t2 & 3;
  int nb = t2 >> 2;
  int col = g * 256 + nb * 64 + w * 16 + l15;
  int k = cb * 32 + kk;
  float v;
  if (col < 768)
    v = (k < 256) ? W_iou[col * 256 + k] : U_iou[col * 512 + (k - 256)];
  else
    v = (k < 256) ? 0.0f : U_f_w[(col - 768) * 512 + (k - 256)];
  Wb2[idx] = (_Float16)v;
}

// x f32 -> f16 once; levels stage x via global_load_lds.
__global__ __launch_bounds__(256) void conv_x16(
    _Float16* __restrict__ x16, const float* __restrict__ x, int n8) {
  int i = blockIdx.x * 256 + threadIdx.x;
  if (i < n8) {
    float4 a = *(const float4*)(x + (size_t)i * 8);
    float4 b = *(const float4*)(x + (size_t)i * 8 + 4);
    *(f16x8*)(x16 + (size_t)i * 8) = pack8(a, b);
  }
}

// =========== wx precompute for nodes < WXN: wx = W_iou @ x, f16 ===========
// Same GEMM structure as the leaf main loop (K=4 chunks, 3 groups); epilogue
// writes wx16[node][g*256+n] via one padded LDS tile (3 group passes).
__global__ __launch_bounds__(256, 2) void wx_kernel(
    const _Float16* __restrict__ x16, const _Float16* __restrict__ Wb2,
    _Float16* __restrict__ wx16, int m) {
  __shared__ __align__(16) char smem[49152];
  f16x8* sA = (f16x8*)smem;

  const int tid = threadIdx.x;
  const int w = tid >> 6;
  const int lane = tid & 63;
  const int l15 = lane & 15;
  const int q = lane >> 4;
  int bx = blockIdx.x;
  const int nb = (bx >> 3) & 3;            // grid = 256 (%32==0): XCD-grouped
  const int r = ((bx >> 5) << 3) + (bx & 7);
  const int pbase = r << 6;
  const int arow = tid >> 3;
  const int akc = tid & 7;
  const int ku = akc ^ (arow & 7);

  int prowA = pbase + arow;
  if (prowA >= m) prowA = pbase;
  int prowB = pbase + arow + 32;
  if (prowB >= m) prowB = pbase;

  const _Float16* bb =
      Wb2 + (size_t)(nb * 4 + w) * (5 * 24 * 512) + l15 * 32 + q * 8;

  f32x4 acc[3][4] = {};
  f16x8 bv0[6], bv1[6];

  auto STAGE = [&](int c, int buf) {
#pragma unroll
    for (int j = 0; j < 2; ++j) {
      const int prow = j ? prowB : prowA;
      const _Float16* src = x16 + ((size_t)prow << 8) + (c << 6) + (ku << 3);
      __builtin_amdgcn_global_load_lds(
          (const __attribute__((address_space(1))) void*)src,
          (__attribute__((address_space(3))) void*)(sA + (buf << 9) +
                                                    (j << 8) + tid),
          16, 0, 0);
    }
  };
  auto LOADB = [&](f16x8 (&bv)[6], int c) {
#pragma unroll
    for (int j = 0; j < 6; ++j)
      bv[j] = *(const f16x8*)(bb + (((j >> 1) * 24 + c * 2 + (j & 1)) << 9));
  };
  auto COMP = [&](int buf, f16x8 (&bv)[6]) {
#pragma unroll
    for (int ks = 0; ks < 2; ++ks) {
      f16x8 af[4];
#pragma unroll
      for (int rf = 0; rf < 4; ++rf) {
        const int rowr = rf * 16 + l15;
        af[rf] = sA[(buf << 9) | (rowr << 3) | ((ks * 4 + q) ^ (rowr & 7))];
      }
#pragma unroll
      for (int g = 0; g < 3; ++g) {
        const f16x8 bf = bv[g * 2 + ks];
#pragma unroll
        for (int rf = 0; rf < 4; ++rf)
          acc[g][rf] = __builtin_amdgcn_mfma_f32_16x16x32_f16(
              af[rf], bf, acc[g][rf], 0, 0, 0);
      }
    }
  };

  STAGE(0, 0);
  STAGE(1, 1);
  STAGE(2, 2);
  STAGE(3, 3);
  LOADB(bv0, 0);
  LOADB(bv1, 1);
  __syncthreads();
  COMP(0, bv0);
  LOADB(bv0, 2);
  COMP(1, bv1);
  LOADB(bv1, 3);
  __builtin_amdgcn_s_barrier();
  COMP(2, bv0);
  COMP(3, bv1);
  __syncthreads();

  // epilogue: per group, scatter acc -> padded tile -> coalesced f16 store
  float* T0 = (float*)smem;  // [64][68]
  const int erow = tid >> 2;
  const int eseg = tid & 3;
  const int p_e = pbase + erow;
  const int scol = (w << 4) + l15;
  const int rbase = erow * 68 + (eseg << 4);
#pragma unroll
  for (int g = 0; g < 3; ++g) {
#pragma unroll
    for (int rf = 0; rf < 4; ++rf)
#pragma unroll
      for (int rr = 0; rr < 4; ++rr)
        T0[(rf * 16 + (q << 2) + rr) * 68 + scol] = acc[g][rf][rr];
    __syncthreads();
    if (p_e < m) {
      float4 v0 = *(const float4*)&T0[rbase];
      float4 v1 = *(const float4*)&T0[rbase + 4];
      float4 v2 = *(const float4*)&T0[rbase + 8];
      float4 v3 = *(const float4*)&T0[rbase + 12];
      _Float16* dst =
          wx16 + (size_t)p_e * 768 + g * 256 + (nb << 6) + (eseg << 4);
      *(f16x8*)dst = pack8(v0, v1);
      *(f16x8*)(dst + 8) = pack8(v2, v3);
    }
    __syncthreads();
  }
}

// ============ unified all-STAGE level kernel (R19, k >= 12 + leaf) =========
template <bool LEAF>
__global__ __launch_bounds__(256, 2) void level16_kernel(
    const _Float16* __restrict__ x16, const float* __restrict__ c0in,
    const _Float16* __restrict__ Wb2, const float* __restrict__ b_iou,
    const float* __restrict__ U_f_b, float* __restrict__ out,
    _Float16* __restrict__ cws, _Float16* __restrict__ hws, int m, int off,
    int coff) {
  constexpr int NG = LEAF ? 3 : 5;
  constexpr int NCH = LEAF ? 4 : 12;
  constexpr int NBU = NG * 2;
  __shared__ __align__(16) char smem[49152];
  f16x8* sA = (f16x8*)smem;

  const int tid = threadIdx.x;
  const int w = tid >> 6;
  const int lane = tid & 63;
  const int l15 = lane & 15;
  const int q = lane >> 4;

  int bx = blockIdx.x, r, nb;
  if ((gridDim.x & 31) == 0) {
    nb = (bx >> 3) & 3;
    r = ((bx >> 5) << 3) + (bx & 7);
  } else {
    r = bx >> 2;
    nb = bx & 3;
  }
  const int pbase = r << 6;
  const int arow = tid >> 3;
  const int akc = tid & 7;
  const int ku = akc ^ (arow & 7);

  int prowA = pbase + arow;
  if (prowA >= m) prowA = pbase;
  int prowB = pbase + arow + 32;
  if (prowB >= m) prowB = pbase;

  const int erow = tid >> 2;
  const int eseg = tid & 3;
  const int p_e = pbase + erow;
  const bool pv = p_e < m;
  const int scol = (w << 4) + l15;
  const int n = (nb << 6) + scol;

  const float bi = b_iou[n];
  const float bo = b_iou[256 + n];
  const float bu = b_iou[512 + n];
  float bf0 = 0.f, bf1 = 0.f;
  if (!LEAF) { bf0 = U_f_b[n]; bf1 = U_f_b[256 + n]; }

  float4 cpre[4];
  f16x8 cpa0, cpa1, cpb0, cpb1;
  if constexpr (LEAF) {
    if (pv) {
      const float* src =
          c0in + (size_t)(off + p_e) * 256 + (nb << 6) + (eseg << 4);
#pragma unroll
      for (int jj = 0; jj < 4; ++jj) cpre[jj] = *(const float4*)(src + jj * 4);
    } else {
#pragma unroll
      for (int jj = 0; jj < 4; ++jj) cpre[jj] = float4{0.f, 0.f, 0.f, 0.f};
    }
  } else {
    if (pv) {
      const _Float16* csrc =
          cws + (size_t)(coff + 2 * p_e) * 256 + (nb << 6) + (eseg << 4);
      cpa0 = *(const f16x8*)csrc;
      cpa1 = *(const f16x8*)(csrc + 8);
      cpb0 = *(const f16x8*)(csrc + 256);
      cpb1 = *(const f16x8*)(csrc + 264);
    } else {
      f16x8 z = {};
      cpa0 = z; cpa1 = z; cpb0 = z; cpb1 = z;
    }
  }

  const _Float16* bb =
      Wb2 + (size_t)(nb * 4 + w) * (5 * 24 * 512) + l15 * 32 + q * 8;

  f32x4 acc[NG][4] = {};

  auto STAGE = [&](int c, int buf) {
#pragma unroll
    for (int j = 0; j < 2; ++j) {
      const int prow = j ? prowB : prowA;
      const _Float16* src;
      if (LEAF || c < 4) {
        src = x16 + ((size_t)(off + prow) << 8) + (c << 6) + (ku << 3);
      } else {
        const int kk = ((c - 4) << 6) + (ku << 3);
        src = hws + ((size_t)(coff + 2 * prow + (kk >> 8)) << 8) + (kk & 255);
      }
      __builtin_amdgcn_global_load_lds(
          (const __attribute__((address_space(1))) void*)src,
          (__attribute__((address_space(3))) void*)(sA + (buf << 9) +
                                                    (j << 8) + tid),
          16, 0, 0);
    }
  };
  auto LOADBn = [&](f16x8 (&bv)[NBU], int c, int nbu) {
#pragma unroll
    for (int j = 0; j < NBU; ++j)
      if (j < nbu)
        bv[j] = *(const f16x8*)(bb + (((j >> 1) * 24 + c * 2 + (j & 1)) << 9));
  };
  auto COMP = [&](int buf, f16x8 (&bv)[NBU], int ng) {
#pragma unroll
    for (int ks = 0; ks < 2; ++ks) {
      f16x8 af[4];
#pragma unroll
      for (int rf = 0; rf < 4; ++rf) {
        const int rowr = rf * 16 + l15;
        af[rf] = sA[(buf << 9) | (rowr << 3) | ((ks * 4 + q) ^ (rowr & 7))];
      }
#pragma unroll
      for (int g = 0; g < NG; ++g)
        if (g < ng) {
          const f16x8 bf = bv[g * 2 + ks];
#pragma unroll
          for (int rf = 0; rf < 4; ++rf)
            acc[g][rf] = __builtin_amdgcn_mfma_f32_16x16x32_f16(
                af[rf], bf, acc[g][rf], 0, 0, 0);
        }
    }
  };

  f16x8 bv0[NBU], bv1[NBU];
  STAGE(0, 0);
  STAGE(1, 1);
  STAGE(2, 2);
  STAGE(3, 3);
  LOADBn(bv0, 0, 6);
  LOADBn(bv1, 1, 6);
  __syncthreads();

#pragma unroll
  for (int p = 0; p < NCH / 2; ++p) {
    const int c = 2 * p;
    if (c + 4 < NCH) {
      STAGE(c + 4, (c + 4) % 6);
      STAGE(c + 5, (c + 5) % 6);
      __builtin_amdgcn_sched_barrier(0);
    }
    COMP(c % 6, bv0, (LEAF || c < 4) ? 3 : 5);
    if (c + 2 < NCH) LOADBn(bv0, c + 2, (LEAF || c + 2 < 4) ? 6 : 10);
    COMP((c + 1) % 6, bv1, (LEAF || c + 1 < 4) ? 3 : 5);
    if (c + 3 < NCH) LOADBn(bv1, c + 3, (LEAF || c + 3 < 4) ? 6 : 10);
    if (c + 2 >= NCH) {
      __syncthreads();
    } else {
      __builtin_amdgcn_s_barrier();
    }
  }

  float* T0 = (float*)smem;
  float* T1 = T0 + 64 * 68;
  const int rbase = erow * 68 + (eseg << 4);

  float cred[16];
  if constexpr (!LEAF) {
    float c0v[16], c1v[16];
#pragma unroll
    for (int j = 0; j < 8; ++j) {
      c0v[j] = (float)cpa0[j]; c0v[8 + j] = (float)cpa1[j];
      c1v[j] = (float)cpb0[j]; c1v[8 + j] = (float)cpb1[j];
    }
#pragma unroll
    for (int rf = 0; rf < 4; ++rf)
#pragma unroll
      for (int rr = 0; rr < 4; ++rr) {
        const int prow = rf * 16 + (q << 2) + rr;
        T0[prow * 68 + scol] = sigP(acc[3][rf][rr] + bf0);
        T1[prow * 68 + scol] = sigP(acc[4][rf][rr] + bf1);
      }
    __syncthreads();
#pragma unroll
    for (int jj = 0; jj < 4; ++jj) {
      float4 f04 = *(const float4*)&T0[rbase + jj * 4];
      float4 f14 = *(const float4*)&T1[rbase + jj * 4];
      cred[jj * 4 + 0] = f04.x * c0v[jj * 4 + 0] + f14.x * c1v[jj * 4 + 0];
      cred[jj * 4 + 1] = f04.y * c0v[jj * 4 + 1] + f14.y * c1v[jj * 4 + 1];
      cred[jj * 4 + 2] = f04.z * c0v[jj * 4 + 2] + f14.z * c1v[jj * 4 + 2];
      cred[jj * 4 + 3] = f04.w * c0v[jj * 4 + 3] + f14.w * c1v[jj * 4 + 3];
    }
    __syncthreads();
  } else {
#pragma unroll
    for (int jj = 0; jj < 4; ++jj) {
      cred[jj * 4 + 0] = cpre[jj].x; cred[jj * 4 + 1] = cpre[jj].y;
      cred[jj * 4 + 2] = cpre[jj].z; cred[jj * 4 + 3] = cpre[jj].w;
    }
  }

#pragma unroll
  for (int rf = 0; rf < 4; ++rf)
#pragma unroll
    for (int rr = 0; rr < 4; ++rr) {
      const int prow = rf * 16 + (q << 2) + rr;
      const float iv = sigP(acc[0][rf][rr] + bi);
      const float uv = tanhP(acc[2][rf][rr] + bu);
      const float ov = sigP(acc[1][rf][rr] + bo);
      T0[prow * 68 + scol] = iv * uv;
      T1[prow * 68 + scol] = ov;
    }
  __syncthreads();

  if (pv) {
    float4 h4[4], c4[4];
#pragma unroll
    for (int jj = 0; jj < 4; ++jj) {
      float4 iu4 = *(const float4*)&T0[rbase + jj * 4];
      float4 o4 = *(const float4*)&T1[rbase + jj * 4];
      float cc;
      cc = iu4.x + cred[jj * 4 + 0]; c4[jj].x = cc; h4[jj].x = o4.x * tanhP(cc);
      cc = iu4.y + cred[jj * 4 + 1]; c4[jj].y = cc; h4[jj].y = o4.y * tanhP(cc);
      cc = iu4.z + cred[jj * 4 + 2]; c4[jj].z = cc; h4[jj].z = o4.z * tanhP(cc);
      cc = iu4.w + cred[jj * 4 + 3]; c4[jj].w = cc; h4[jj].w = o4.w * tanhP(cc);
    }
    const size_t ob = (size_t)(off + p_e) * 256 + (nb << 6) + (eseg << 4);
    float* dst = out + ob;
#pragma unroll
    for (int jj = 0; jj < 4; ++jj) *(float4*)(dst + jj * 4) = h4[jj];
    *(f16x8*)(hws + ob) = pack8(h4[0], h4[1]);
    *(f16x8*)(hws + ob + 8) = pack8(h4[2], h4[3]);
    *(f16x8*)(cws + ob) = pack8(c4[0], c4[1]);
    *(f16x8*)(cws + ob + 8) = pack8(c4[2], c4[3]);
  }
}

// ===== shortened tail kernel (k <= 11): 8 h-chunks; wx added in epilogue ====
__global__ __launch_bounds__(256, 2) void tail8_kernel(
    const _Float16* __restrict__ Wb2, const float* __restrict__ b_iou,
    const float* __restrict__ U_f_b, float* __restrict__ out,
    _Float16* __restrict__ cws, _Float16* __restrict__ hws,
    const _Float16* __restrict__ wx16, int m, int off, int coff) {
  __shared__ __align__(16) char smem[49152];
  f16x8* sA = (f16x8*)smem;

  const int tid = threadIdx.x;
  const int w = tid >> 6;
  const int lane = tid & 63;
  const int l15 = lane & 15;
  const int q = lane >> 4;

  int bx = blockIdx.x, r, nb;
  if ((gridDim.x & 31) == 0) {
    nb = (bx >> 3) & 3;
    r = ((bx >> 5) << 3) + (bx & 7);
  } else {
    r = bx >> 2;
    nb = bx & 3;
  }
  const int pbase = r << 6;
  const int arow = tid >> 3;
  const int akc = tid & 7;
  const int ku = akc ^ (arow & 7);

  int prowA = pbase + arow;
  if (prowA >= m) prowA = pbase;
  int prowB = pbase + arow + 32;
  if (prowB >= m) prowB = pbase;

  const int erow = tid >> 2;
  const int eseg = tid & 3;
  const int p_e = pbase + erow;
  const bool pv = p_e < m;
  const int scol = (w << 4) + l15;
  const int n = (nb << 6) + scol;

  // hoisted epilogue inputs: biases, c-children, and wx (48 scalars)
  const float bi = b_iou[n];
  const float bo = b_iou[256 + n];
  const float bu = b_iou[512 + n];
  const float bf0 = U_f_b[n], bf1 = U_f_b[256 + n];

  f16x8 cpa0, cpa1, cpb0, cpb1;
  if (pv) {
    const _Float16* csrc =
        cws + (size_t)(coff + 2 * p_e) * 256 + (nb << 6) + (eseg << 4);
    cpa0 = *(const f16x8*)csrc;
    cpa1 = *(const f16x8*)(csrc + 8);
    cpb0 = *(const f16x8*)(csrc + 256);
    cpb1 = *(const f16x8*)(csrc + 264);
  } else {
    f16x8 z = {};
    cpa0 = z; cpa1 = z; cpb0 = z; cpb1 = z;
  }

  float wxv[3][4][4];
#pragma unroll
  for (int g = 0; g < 3; ++g)
#pragma unroll
    for (int rf = 0; rf < 4; ++rf)
#pragma unroll
      for (int rr = 0; rr < 4; ++rr) {
        int prow = pbase + rf * 16 + (q << 2) + rr;
        if (prow >= m) prow = pbase;
        wxv[g][rf][rr] =
            (float)wx16[(size_t)(off + prow) * 768 + g * 256 + n];
      }

  const _Float16* bb =
      Wb2 + (size_t)(nb * 4 + w) * (5 * 24 * 512) + l15 * 32 + q * 8;

  f32x4 acc[5][4] = {};

  auto STAGE = [&](int c, int buf) {  // c = h-chunk 0..7
#pragma unroll
    for (int j = 0; j < 2; ++j) {
      const int prow = j ? prowB : prowA;
      const int kk = (c << 6) + (ku << 3);
      const _Float16* src =
          hws + ((size_t)(coff + 2 * prow + (kk >> 8)) << 8) + (kk & 255);
      __builtin_amdgcn_global_load_lds(
          (const __attribute__((address_space(1))) void*)src,
          (__attribute__((address_space(3))) void*)(sA + (buf << 9) +
                                                    (j << 8) + tid),
          16, 0, 0);
    }
  };
  auto LOADB = [&](f16x8 (&bv)[10], int c) {  // B chunk index = c+4
#pragma unroll
    for (int j = 0; j < 10; ++j)
      bv[j] =
          *(const f16x8*)(bb + (((j >> 1) * 24 + (c + 4) * 2 + (j & 1)) << 9));
  };
  auto COMP = [&](int buf, f16x8 (&bv)[10]) {
#pragma unroll
    for (int ks = 0; ks < 2; ++ks) {
      f16x8 af[4];
#pragma unroll
      for (int rf = 0; rf < 4; ++rf) {
        const int rowr = rf * 16 + l15;
        af[rf] = sA[(buf << 9) | (rowr << 3) | ((ks * 4 + q) ^ (rowr & 7))];
      }
#pragma unroll
      for (int g = 0; g < 5; ++g) {
        const f16x8 bf = bv[g * 2 + ks];
#pragma unroll
        for (int rf = 0; rf < 4; ++rf)
          acc[g][rf] = __builtin_amdgcn_mfma_f32_16x16x32_f16(
              af[rf], bf, acc[g][rf], 0, 0, 0);
      }
    }
  };

  f16x8 bv0[10], bv1[10];
  STAGE(0, 0);
  STAGE(1, 1);
  STAGE(2, 2);
  STAGE(3, 3);
  LOADB(bv0, 0);
  LOADB(bv1, 1);
  __syncthreads();

#pragma unroll
  for (int p = 0; p < 4; ++p) {
    const int c = 2 * p;
    if (c + 4 < 8) {
      STAGE(c + 4, (c + 4) % 6);
      STAGE(c + 5, (c + 5) % 6);
      __builtin_amdgcn_sched_barrier(0);
    }
    COMP(c % 6, bv0);
    if (c + 2 < 8) LOADB(bv0, c + 2);
    COMP((c + 1) % 6, bv1);
    if (c + 3 < 8) LOADB(bv1, c + 3);
    if (c + 2 >= 8) {
      __syncthreads();
    } else {
      __builtin_amdgcn_s_barrier();
    }
  }

  // epilogue (iou gets +wx)
  float* T0 = (float*)smem;
  float* T1 = T0 + 64 * 68;
  const int rbase = erow * 68 + (eseg << 4);

  float c0v[16], c1v[16];
#pragma unroll
  for (int j = 0; j < 8; ++j) {
    c0v[j] = (float)cpa0[j]; c0v[8 + j] = (float)cpa1[j];
    c1v[j] = (float)cpb0[j]; c1v[8 + j] = (float)cpb1[j];
  }
#pragma unroll
  for (int rf = 0; rf < 4; ++rf)
#pragma unroll
    for (int rr = 0; rr < 4; ++rr) {
      const int prow = rf * 16 + (q << 2) + rr;
      T0[prow * 68 + scol] = sigP(acc[3][rf][rr] + bf0);
      T1[prow * 68 + scol] = sigP(acc[4][rf][rr] + bf1);
    }
  __syncthreads();
  float cred[16];
#pragma unroll
  for (int jj = 0; jj < 4; ++jj) {
    float4 f04 = *(const float4*)&T0[rbase + jj * 4];
    float4 f14 = *(const float4*)&T1[rbase + jj * 4];
    cred[jj * 4 + 0] = f04.x * c0v[jj * 4 + 0] + f14.x * c1v[jj * 4 + 0];
    cred[jj * 4 + 1] = f04.y * c0v[jj * 4 + 1] + f14.y * c1v[jj * 4 + 1];
    cred[jj * 4 + 2] = f04.z * c0v[jj * 4 + 2] + f14.z * c1v[jj * 4 + 2];
    cred[jj * 4 + 3] = f04.w * c0v[jj * 4 + 3] + f14.w * c1v[jj * 4 + 3];
  }
  __syncthreads();

#pragma unroll
  for (int rf = 0; rf < 4; ++rf)
#pragma unroll
    for (int rr = 0; rr < 4; ++rr) {
      const int prow = rf * 16 + (q << 2) + rr;
      const float iv = sigP(acc[0][rf][rr] + wxv[0][rf][rr] + bi);
      const float uv = tanhP(acc[2][rf][rr] + wxv[2][rf][rr] + bu);
      const float ov = sigP(acc[1][rf][rr] + wxv[1][rf][rr] + bo);
      T0[prow * 68 + scol] = iv * uv;
      T1[prow * 68 + scol] = ov;
    }
  __syncthreads();

  if (pv) {
    float4 h4[4], c4[4];
#pragma unroll
    for (int jj = 0; jj < 4; ++jj) {
      float4 iu4 = *(const float4*)&T0[rbase + jj * 4];
      float4 o4 = *(const float4*)&T1[rbase + jj * 4];
      float cc;
      cc = iu4.x + cred[jj * 4 + 0]; c4[jj].x = cc; h4[jj].x = o4.x * tanhP(cc);
      cc = iu4.y + cred[jj * 4 + 1]; c4[jj].y = cc; h4[jj].y = o4.y * tanhP(cc);
      cc = iu4.z + cred[jj * 4 + 2]; c4[jj].z = cc; h4[jj].z = o4.z * tanhP(cc);
      cc = iu4.w + cred[jj * 4 + 3]; c4[jj].w = cc; h4[jj].w = o4.w * tanhP(cc);
    }
    const size_t ob = (size_t)(off + p_e) * 256 + (nb << 6) + (eseg << 4);
    float* dst = out + ob;
#pragma unroll
    for (int jj = 0; jj < 4; ++jj) *(float4*)(dst + jj * 4) = h4[jj];
    *(f16x8*)(hws + ob) = pack8(h4[0], h4[1]);
    *(f16x8*)(hws + ob + 8) = pack8(h4[2], h4[3]);
    *(f16x8*)(cws + ob) = pack8(c4[0], c4[1]);
    *(f16x8*)(cws + ob + 8) = pack8(c4[2], c4[3]);
  }
}

// ==================== R12 fallback (no x16 workspace) ======================
template <bool LEAF, bool H16, typename CT>
__global__ __launch_bounds__(256, 2) void level_kernel(
    const float* __restrict__ x, const float* __restrict__ c0in,
    const _Float16* __restrict__ Wb2, const float* __restrict__ b_iou,
    const float* __restrict__ U_f_b, float* __restrict__ out,
    CT* __restrict__ cws, _Float16* __restrict__ hws, int m, int off,
    int coff) {
  constexpr int NG = LEAF ? 3 : 5;
  constexpr int NCH = LEAF ? 4 : 12;
  constexpr int NBU = NG * 2;
  __shared__ __align__(16) char smem[34816];
  f16x8* sA = (f16x8*)smem;

  const int tid = threadIdx.x;
  const int w = tid >> 6;
  const int lane = tid & 63;
  const int l15 = lane & 15;
  const int q = lane >> 4;
  int bx = blockIdx.x, r, nb;
  if ((gridDim.x & 31) == 0) {
    nb = (bx >> 3) & 3;
    r = ((bx >> 5) << 3) + (bx & 7);
  } else {
    r = bx >> 2;
    nb = bx & 3;
  }
  const int pbase = r << 6;
  const int arow = tid >> 3;
  const int akc = tid & 7;

  const _Float16* bb =
      Wb2 + (size_t)(nb * 4 + w) * (5 * 24 * 512) + l15 * 32 + q * 8;

  f32x4 acc[NG][4] = {};

  auto LOADA = [&](float4 (&ax)[2][2], f16x8 (&ah)[2], int c) {
    const int k0 = (c << 6) + (akc << 3);
#pragma unroll
    for (int j = 0; j < 2; ++j) {
      const int row = arow + j * 32;
      const int p = pbase + row;
      const bool xpart = LEAF || c < 4;
      if (p < m) {
        if (xpart) {
          const float* src = x + (size_t)(off + p) * 256 + k0;
          ax[j][0] = *(const float4*)src;
          ax[j][1] = *(const float4*)(src + 4);
        } else if (H16) {
          ah[j] = *(const f16x8*)(hws + (size_t)(coff + 2 * p) * 256 +
                                  (k0 - 256));
        } else {
          const float* src = out + (size_t)(coff + 2 * p) * 256 + (k0 - 256);
          ax[j][0] = *(const float4*)src;
          ax[j][1] = *(const float4*)(src + 4);
        }
      } else {
        ax[j][0] = float4{0.f, 0.f, 0.f, 0.f};
        ax[j][1] = float4{0.f, 0.f, 0.f, 0.f};
        f16x8 z = {};
        ah[j] = z;
      }
    }
  };
  auto WRITEA = [&](float4 (&ax)[2][2], f16x8 (&ah)[2], int c) {
#pragma unroll
    for (int j = 0; j < 2; ++j) {
      const int row = arow + j * 32;
      f16x8 v;
      if (H16 && !LEAF && c >= 4) v = ah[j];
      else v = pack8(ax[j][0], ax[j][1]);
      sA[((c & 1) << 9) | (row << 3) | (akc ^ (row & 7))] = v;
    }
  };
  auto LOADB = [&](f16x8 (&bv)[NBU], int c) {
#pragma unroll
    for (int j = 0; j < NBU; ++j)
      bv[j] = *(const f16x8*)(bb + (((j >> 1) * 24 + c * 2 + (j & 1)) << 9));
  };
  auto COMPUTE = [&](int buf, f16x8 (&bv)[NBU]) {
#pragma unroll
    for (int ks = 0; ks < 2; ++ks) {
      f16x8 af[4];
#pragma unroll
      for (int rf = 0; rf < 4; ++rf) {
        const int row = rf * 16 + l15;
        af[rf] = sA[(buf << 9) | (row << 3) | ((ks * 4 + q) ^ (row & 7))];
      }
#pragma unroll
      for (int g = 0; g < NG; ++g) {
        const f16x8 bf = bv[g * 2 + ks];
#pragma unroll
        for (int rf = 0; rf < 4; ++rf)
          acc[g][rf] = __builtin_amdgcn_mfma_f32_16x16x32_f16(
              af[rf], bf, acc[g][rf], 0, 0, 0);
      }
    }
  };

  float4 axA[2][2], axB[2][2];
  f16x8 ahA[2], ahB[2];
  f16x8 bvA[NBU], bvB[NBU];

  LOADA(axA, ahA, 0);
  LOADB(bvA, 0);
  WRITEA(axA, ahA, 0);
  LOADA(axB, ahB, 1);
  LOADB(bvB, 1);
  __syncthreads();

  for (int c = 0; c < NCH; c += 2) {
    if (c + 2 < NCH) LOADA(axA, ahA, c + 2);
    COMPUTE(0, bvA);
    WRITEA(axB, ahB, c + 1);
    if (c + 2 < NCH) LOADB(bvA, c + 2);
    __syncthreads();
    if (c + 3 < NCH) LOADA(axB, ahB, c + 3);
    COMPUTE(1, bvB);
    if (c + 2 < NCH) {
      WRITEA(axA, ahA, c + 2);
      if (c + 3 < NCH) LOADB(bvB, c + 3);
      __syncthreads();
    }
  }
  __syncthreads();

  const int erow = tid >> 2;
  const int eseg = tid & 3;
  const int p_e = pbase + erow;
  const bool pv = p_e < m;
  float* T0 = (float*)smem;
  float* T1 = T0 + 64 * 68;
  const int scol = (w << 4) + l15;
  const int n = (nb << 6) + scol;
  const int rbase = erow * 68 + (eseg << 4);

  float cred[16];
  if constexpr (!LEAF) {
    float c0v[16], c1v[16];
    if (pv) {
      const CT* csrc =
          cws + (size_t)(coff + 2 * p_e) * 256 + (nb << 6) + (eseg << 4);
      if constexpr (sizeof(CT) == 2) {
        f16x8 a0 = *(const f16x8*)csrc;
        f16x8 a1 = *(const f16x8*)(csrc + 8);
        f16x8 b0 = *(const f16x8*)(csrc + 256);
        f16x8 b1 = *(const f16x8*)(csrc + 264);
#pragma unroll
        for (int j = 0; j < 8; ++j) {
          c0v[j] = (float)a0[j]; c0v[8 + j] = (float)a1[j];
          c1v[j] = (float)b0[j]; c1v[8 + j] = (float)b1[j];
        }
      } else {
#pragma unroll
        for (int jj = 0; jj < 4; ++jj) {
          float4 v0 = *(const float4*)((const float*)csrc + jj * 4);
          float4 v1 = *(const float4*)((const float*)csrc + 256 + jj * 4);
          c0v[jj * 4 + 0] = v0.x; c0v[jj * 4 + 1] = v0.y;
          c0v[jj * 4 + 2] = v0.z; c0v[jj * 4 + 3] = v0.w;
          c1v[jj * 4 + 0] = v1.x; c1v[jj * 4 + 1] = v1.y;
          c1v[jj * 4 + 2] = v1.z; c1v[jj * 4 + 3] = v1.w;
        }
      }
    } else {
#pragma unroll
      for (int j = 0; j < 16; ++j) { c0v[j] = 0.f; c1v[j] = 0.f; }
    }
    const float bf0 = U_f_b[n], bf1 = U_f_b[256 + n];
#pragma unroll
    for (int rf = 0; rf < 4; ++rf)
#pragma unroll
      for (int rr = 0; rr < 4; ++rr) {
        const int prow = rf * 16 + (q << 2) + rr;
        T0[prow * 68 + scol] = sigP(acc[3][rf][rr] + bf0);
        T1[prow * 68 + scol] = sigP(acc[4][rf][rr] + bf1);
      }
    __syncthreads();
#pragma unroll
    for (int jj = 0; jj < 4; ++jj) {
      float4 f04 = *(const float4*)&T0[rbase + jj * 4];
      float4 f14 = *(const float4*)&T1[rbase + jj * 4];
      cred[jj * 4 + 0] = f04.x * c0v[jj * 4 + 0] + f14.x * c1v[jj * 4 + 0];
      cred[jj * 4 + 1] = f04.y * c0v[jj * 4 + 1] + f14.y * c1v[jj * 4 + 1];
      cred[jj * 4 + 2] = f04.z * c0v[jj * 4 + 2] + f14.z * c1v[jj * 4 + 2];
      cred[jj * 4 + 3] = f04.w * c0v[jj * 4 + 3] + f14.w * c1v[jj * 4 + 3];
    }
    __syncthreads();
  } else {
    if (pv) {
      const float* src =
          c0in + (size_t)(off + p_e) * 256 + (nb << 6) + (eseg << 4);
#pragma unroll
      for (int jj = 0; jj < 4; ++jj) {
        float4 v = *(const float4*)(src + jj * 4);
        cred[jj * 4 + 0] = v.x; cred[jj * 4 + 1] = v.y;
        cred[jj * 4 + 2] = v.z; cred[jj * 4 + 3] = v.w;
      }
    } else {
#pragma unroll
      for (int j = 0; j < 16; ++j) cred[j] = 0.f;
    }
  }

  {
    const float bi = b_iou[n], bo = b_iou[256 + n], bu = b_iou[512 + n];
#pragma unroll
    for (int rf = 0; rf < 4; ++rf)
#pragma unroll
      for (int rr = 0; rr < 4; ++rr) {
        const int prow = rf * 16 + (q << 2) + rr;
        const float iv = sigP(acc[0][rf][rr] + bi);
        const float uv = tanhP(acc[2][rf][rr] + bu);
        const float ov = sigP(acc[1][rf][rr] + bo);
        T0[prow * 68 + scol] = iv * uv;
        T1[prow * 68 + scol] = ov;
      }
  }
  __syncthreads();

  if (pv) {
    float4 h4[4], c4[4];
#pragma unroll
    for (int jj = 0; jj < 4; ++jj) {
      float4 iu4 = *(const float4*)&T0[rbase + jj * 4];
      float4 o4 = *(const float4*)&T1[rbase + jj * 4];
      float cc;
      cc = iu4.x + cred[jj * 4 + 0]; c4[jj].x = cc; h4[jj].x = o4.x * tanhP(cc);
      cc = iu4.y + cred[jj * 4 + 1]; c4[jj].y = cc; h4[jj].y = o4.y * tanhP(cc);
      cc = iu4.z + cred[jj * 4 + 2]; c4[jj].z = cc; h4[jj].z = o4.z * tanhP(cc);
      cc = iu4.w + cred[jj * 4 + 3]; c4[jj].w = cc; h4[jj].w = o4.w * tanhP(cc);
    }
    const size_t ob = (size_t)(off + p_e) * 256 + (nb << 6) + (eseg << 4);
    float* dst = out + ob;
#pragma unroll
    for (int jj = 0; jj < 4; ++jj) *(float4*)(dst + jj * 4) = h4[jj];
    if constexpr (H16) {
      *(f16x8*)(hws + ob) = pack8(h4[0], h4[1]);
      *(f16x8*)(hws + ob + 8) = pack8(h4[2], h4[3]);
    }
    if constexpr (sizeof(CT) == 2) {
      *(f16x8*)((_Float16*)cws + ob) = pack8(c4[0], c4[1]);
      *(f16x8*)((_Float16*)cws + ob + 8) = pack8(c4[2], c4[3]);
    } else {
      float* cdst = (float*)cws + ob;
#pragma unroll
      for (int jj = 0; jj < 4; ++jj) *(float4*)(cdst + jj * 4) = c4[jj];
    }
  }
}

template <bool H16, typename CT>
static void run_levels(const float* x, const float* c0, const _Float16* Wb2,
                       const float* b_iou, const float* U_f_b, float* out,
                       CT* cws, _Float16* hws, hipStream_t stream) {
  level_kernel<true, H16, CT><<<dim3(4096), 256, 0, stream>>>(
      x, c0, Wb2, b_iou, U_f_b, out, cws, hws, 65536, 65535, 0);
  for (int k = DEPTH - 2; k >= 0; --k) {
    const int m = 1 << k;
    const int R = (m + 63) / 64;
    level_kernel<false, H16, CT><<<dim3(R * 4), 256, 0, stream>>>(
        x, c0, Wb2, b_iou, U_f_b, out, cws, hws, m, m - 1, 2 * m - 1);
  }
}

extern "C" void kernel_launch(void* const* d_in, const int* in_sizes, int n_in,
                              void* d_out, int out_size, void* d_ws, size_t ws_size,
                              hipStream_t stream) {
  const float* x     = (const float*)d_in[0];
  // d_in[1] = h0 (unused by the reference's math)
  const float* c0    = (const float*)d_in[2];
  const float* W_iou = (const float*)d_in[3];
  const float* U_iou = (const float*)d_in[4];
  const float* b_iou = (const float*)d_in[5];
  const float* U_f_w = (const float*)d_in[6];
  const float* U_f_b = (const float*)d_in[7];
  float* out = (float*)d_out;

  char* ws = (char*)d_ws;
  const size_t wbBytes = (size_t)1280 * 768 * 2;  // 1.97 MB, 16B-aligned
  _Float16* Wb2 = (_Float16*)ws;
  build_wb2<<<3840, 256, 0, stream>>>(Wb2, W_iou, U_iou, U_f_w);

  const size_t cElems = (size_t)NNODES * 256;  // 33.55M
  const size_t wxBytes = (size_t)(WXN - 1) * 768 * 2 + 256;  // ~6.3 MB
  char* p1 = ws + wbBytes;
  const bool haveX16 = ws_size >= wbBytes + cElems * 6;
  const bool haveWx = ws_size >= wbBytes + cElems * 6 + wxBytes;

  if (haveX16) {
    // tiers: [c16][h16][x16][wx16?]
    _Float16* cws = (_Float16*)p1;
    _Float16* hws = (_Float16*)(p1 + cElems * 2);
    _Float16* x16 = (_Float16*)(p1 + cElems * 4);
    _Float16* wx16 = (_Float16*)(p1 + cElems * 6);
    const int n8 = (int)(cElems / 8);
    conv_x16<<<dim3((n8 + 255) / 256), 256, 0, stream>>>(x16, x, n8);
    if (haveWx) {
      // wx for nodes 0..WXN-2 (levels k<=11); 64 row-blocks x4 nb = 256
      wx_kernel<<<dim3(256), 256, 0, stream>>>(x16, Wb2, wx16, WXN - 1);
    }
    level16_kernel<true><<<dim3(4096), 256, 0, stream>>>(
        x16, c0, Wb2, b_iou, U_f_b, out, cws, hws, 65536, 65535, 0);
    const int kmin16 = haveWx ? 12 : 0;
    for (int k = DEPTH - 2; k >= kmin16; --k) {
      const int m = 1 << k;
      const int R = (m + 63) / 64;
      level16_kernel<false><<<dim3(R * 4), 256, 0, stream>>>(
          x16, c0, Wb2, b_iou, U_f_b, out, cws, hws, m, m - 1, 2 * m - 1);
    }
    if (haveWx) {
      for (int k = 11; k >= 0; --k) {
        const int m = 1 << k;
        const int R = (m + 63) / 64;
        tail8_kernel<<<dim3(R * 4), 256, 0, stream>>>(
            Wb2, b_iou, U_f_b, out, cws, hws, wx16, m, m - 1, 2 * m - 1);
      }
    }
  } else if (ws_size >= wbBytes + cElems * 2 + cElems * 2) {
    run_levels<true, _Float16>(x, c0, Wb2, b_iou, U_f_b, out, (_Float16*)p1,
                               (_Float16*)(p1 + cElems * 2), stream);
  } else if (ws_size >= wbBytes + cElems * 4) {
    run_levels<false, float>(x, c0, Wb2, b_iou, U_f_b, out, (float*)p1,
                             nullptr, stream);
  } else {
    run_levels<false, _Float16>(x, c0, Wb2, b_iou, U_f_b, out, (_Float16*)p1,
                                nullptr, stream);
  }
}

// Round 21
// 453.368 us; speedup vs baseline: 1.0277x; 1.0277x over previous
//
#include <hip/hip_runtime.h>
#include <math.h>

#define DEPTH 17
#define NNODES ((1 << DEPTH) - 1)

typedef _Float16 f16x8 __attribute__((ext_vector_type(8)));
typedef float f32x4 __attribute__((ext_vector_type(4)));

// [5/4] Pade tanh, clamped at |x|<=3.4: max err ~1.3e-3 (loose 1.7e-2 tol)
__device__ __forceinline__ float tanhP(float x) {
  float t = fminf(fmaxf(x, -3.4f), 3.4f);
  float s = t * t;
  float num = t * (945.0f + s * (105.0f + s));
  float den = 945.0f + s * (420.0f + 15.0f * s);
  return num * __builtin_amdgcn_rcpf(den);
}
__device__ __forceinline__ float sigP(float x) {
  return 0.5f + 0.5f * tanhP(0.5f * x);
}
__device__ __forceinline__ f16x8 pack8(const float4& a, const float4& b) {
  f16x8 r;
  r[0] = (_Float16)a.x; r[1] = (_Float16)a.y;
  r[2] = (_Float16)a.z; r[3] = (_Float16)a.w;
  r[4] = (_Float16)b.x; r[5] = (_Float16)b.y;
  r[6] = (_Float16)b.z; r[7] = (_Float16)b.w;
  return r;
}

// Lane-order-packed weights: for each (nb, w, g, cb) a 16x32 f16 tile stored
// so lane (q*16+l15) holds elems l15*32 + q*8 .. +7 -> one wave B-fragment =
// contiguous 1 KB, coalesced, L2-resident (1.97 MB total).
__global__ __launch_bounds__(256) void build_wb2(
    _Float16* __restrict__ Wb2, const float* __restrict__ W_iou,
    const float* __restrict__ U_iou, const float* __restrict__ U_f_w) {
  int idx = blockIdx.x * 256 + threadIdx.x;  // grid covers 1280*768 exactly
  int within = idx & 511;                    // l15*32 + kk
  int blk = idx >> 9;                        // ((nb*4+w)*5 + g)*24 + cb
  int l15 = within >> 5;
  int kk = within & 31;
  int cb = blk % 24;
  int t = blk / 24;
  int g = t % 5;
  int t2 = t / 5;
  int w = t2 & 3;
  int nb = t2 >> 2;
  int col = g * 256 + nb * 64 + w * 16 + l15;
  int k = cb * 32 + kk;
  float v;
  if (col < 768)
    v = (k < 256) ? W_iou[col * 256 + k] : U_iou[col * 512 + (k - 256)];
  else
    v = (k < 256) ? 0.0f : U_f_w[(col - 768) * 512 + (k - 256)];
  Wb2[idx] = (_Float16)v;
}

// x f32 -> f16 once; all levels then stage x via global_load_lds.
__global__ __launch_bounds__(256) void conv_x16(
    _Float16* __restrict__ x16, const float* __restrict__ x, int n8) {
  int i = blockIdx.x * 256 + threadIdx.x;
  if (i < n8) {
    float4 a = *(const float4*)(x + (size_t)i * 8);
    float4 b = *(const float4*)(x + (size_t)i * 8 + 4);
    *(f16x8*)(x16 + (size_t)i * 8) = pack8(a, b);
  }
}

// ============ unified all-STAGE level kernel (x16 + h16/c16 ws) ============
// Block tile 64 rows x 64 n (x NG groups); 4 waves; wave w owns all 64 rows
// for n = nb*64 + w*16 + l15 -> wave-local MFMA, LDS-transposed epilogue.
// A: every chunk via global_load_lds (x16 / hws f16), linear dest + inverse-
// swizzled source (rule 21); six-buffer rotation staged two pairs ahead;
// pair boundary = plain s_barrier (in-order vmem retire + B-use waits imply
// stage completion — verified R16). B: register ping-pong from lane-packed
// Wb2 (L2-resident). HOISTED EPILOGUE INPUTS (R19): the c-input tile (c0 /
// c-children) and the 5 bias scalars do NOT depend on the GEMM — issued at
// kernel start into registers, their ~700cy HBM latency hides under the
// whole main loop instead of serializing after the last barrier.
// f-gate groups (g=3,4) skipped for chunks<4 (zero Wb2 block). Epilogue:
// padded [64][68] f32 LDS tiles; Pade gates (no v_exp).
// NOTE: occupancy is pinned at 2 waves/SIMD by the 128-reg granularity
// bucket (80 acc + ~120 arch); R15-R18 proved scheduling/staging tweaks
// can't unpin it. R20 proved the tail is launch-latency-bound, not K-bound.
// NOTE: n-split is load-bearing (R9). Tail stays per-level LAUNCHES (R8/R14:
// launch boundary is the cheapest cross-XCD barrier).
template <bool LEAF>
__global__ __launch_bounds__(256, 2) void level16_kernel(
    const _Float16* __restrict__ x16, const float* __restrict__ c0in,
    const _Float16* __restrict__ Wb2, const float* __restrict__ b_iou,
    const float* __restrict__ U_f_b, float* __restrict__ out,
    _Float16* __restrict__ cws, _Float16* __restrict__ hws, int m, int off,
    int coff) {
  constexpr int NG = LEAF ? 3 : 5;
  constexpr int NCH = LEAF ? 4 : 12;
  constexpr int NBU = NG * 2;
  __shared__ __align__(16) char smem[49152];  // main: 6x8KB bufs; epi: tiles
  f16x8* sA = (f16x8*)smem;

  const int tid = threadIdx.x;
  const int w = tid >> 6;
  const int lane = tid & 63;
  const int l15 = lane & 15;
  const int q = lane >> 4;

  int bx = blockIdx.x, r, nb;
  if ((gridDim.x & 31) == 0) {  // XCD-grouped: nb-splits share bid%8
    nb = (bx >> 3) & 3;
    r = ((bx >> 5) << 3) + (bx & 7);
  } else {
    r = bx >> 2;
    nb = bx & 3;
  }
  const int pbase = r << 6;
  const int arow = tid >> 3;
  const int akc = tid & 7;
  const int ku = akc ^ (arow & 7);  // same for rows arow and arow+32

  int prowA = pbase + arow;
  if (prowA >= m) prowA = pbase;
  int prowB = pbase + arow + 32;
  if (prowB >= m) prowB = pbase;

  // ---- R19: hoisted epilogue inputs (GEMM-independent) ----
  const int erow = tid >> 2;
  const int eseg = tid & 3;
  const int p_e = pbase + erow;
  const bool pv = p_e < m;
  const int scol = (w << 4) + l15;
  const int n = (nb << 6) + scol;

  const float bi = b_iou[n];
  const float bo = b_iou[256 + n];
  const float bu = b_iou[512 + n];
  float bf0 = 0.f, bf1 = 0.f;
  if (!LEAF) { bf0 = U_f_b[n]; bf1 = U_f_b[256 + n]; }

  float4 cpre[4];          // leaf: c0 row segment (f32)
  f16x8 cpa0, cpa1, cpb0, cpb1;  // internal: children c16 segments
  if constexpr (LEAF) {
    if (pv) {
      const float* src =
          c0in + (size_t)(off + p_e) * 256 + (nb << 6) + (eseg << 4);
#pragma unroll
      for (int jj = 0; jj < 4; ++jj) cpre[jj] = *(const float4*)(src + jj * 4);
    } else {
#pragma unroll
      for (int jj = 0; jj < 4; ++jj) cpre[jj] = float4{0.f, 0.f, 0.f, 0.f};
    }
  } else {
    if (pv) {
      const _Float16* csrc =
          cws + (size_t)(coff + 2 * p_e) * 256 + (nb << 6) + (eseg << 4);
      cpa0 = *(const f16x8*)csrc;
      cpa1 = *(const f16x8*)(csrc + 8);
      cpb0 = *(const f16x8*)(csrc + 256);
      cpb1 = *(const f16x8*)(csrc + 264);
    } else {
      f16x8 z = {};
      cpa0 = z; cpa1 = z; cpb0 = z; cpb1 = z;
    }
  }

  const _Float16* bb =
      Wb2 + (size_t)(nb * 4 + w) * (5 * 24 * 512) + l15 * 32 + q * 8;

  f32x4 acc[NG][4] = {};

  auto STAGE = [&](int c, int buf) {
#pragma unroll
    for (int j = 0; j < 2; ++j) {
      const int prow = j ? prowB : prowA;
      const _Float16* src;
      if (LEAF || c < 4) {
        src = x16 + ((size_t)(off + prow) << 8) + (c << 6) + (ku << 3);
      } else {
        const int kk = ((c - 4) << 6) + (ku << 3);
        src = hws + ((size_t)(coff + 2 * prow + (kk >> 8)) << 8) + (kk & 255);
      }
      __builtin_amdgcn_global_load_lds(
          (const __attribute__((address_space(1))) void*)src,
          (__attribute__((address_space(3))) void*)(sA + (buf << 9) +
                                                    (j << 8) + tid),
          16, 0, 0);
    }
  };
  auto LOADBn = [&](f16x8 (&bv)[NBU], int c, int nbu) {
#pragma unroll
    for (int j = 0; j < NBU; ++j)
      if (j < nbu)
        bv[j] = *(const f16x8*)(bb + (((j >> 1) * 24 + c * 2 + (j & 1)) << 9));
  };
  auto COMP = [&](int buf, f16x8 (&bv)[NBU], int ng) {
#pragma unroll
    for (int ks = 0; ks < 2; ++ks) {
      f16x8 af[4];
#pragma unroll
      for (int rf = 0; rf < 4; ++rf) {
        const int rowr = rf * 16 + l15;
        af[rf] = sA[(buf << 9) | (rowr << 3) | ((ks * 4 + q) ^ (rowr & 7))];
      }
#pragma unroll
      for (int g = 0; g < NG; ++g)
        if (g < ng) {
          const f16x8 bf = bv[g * 2 + ks];
#pragma unroll
          for (int rf = 0; rf < 4; ++rf)
            acc[g][rf] = __builtin_amdgcn_mfma_f32_16x16x32_f16(
                af[rf], bf, acc[g][rf], 0, 0, 0);
        }
    }
  };

  f16x8 bv0[NBU], bv1[NBU];
  // prologue: stage chunks 0..3 (2 pairs deep), then B(0),B(1); full drain
  // (also retires the hoisted epilogue loads, which overlap the stages).
  STAGE(0, 0);
  STAGE(1, 1);
  STAGE(2, 2);
  STAGE(3, 3);
  LOADBn(bv0, 0, 6);
  LOADBn(bv1, 1, 6);
  __syncthreads();  // one-time vmcnt(0) drain

#pragma unroll
  for (int p = 0; p < NCH / 2; ++p) {
    const int c = 2 * p;
    if (c + 4 < NCH) {
      STAGE(c + 4, (c + 4) % 6);
      STAGE(c + 5, (c + 5) % 6);
      __builtin_amdgcn_sched_barrier(0);  // stages stay OLDEST vmem this pair
    }
    COMP(c % 6, bv0, (LEAF || c < 4) ? 3 : 5);
    if (c + 2 < NCH) LOADBn(bv0, c + 2, (LEAF || c + 2 < 4) ? 6 : 10);
    COMP((c + 1) % 6, bv1, (LEAF || c + 1 < 4) ? 3 : 5);
    if (c + 3 < NCH) LOADBn(bv1, c + 3, (LEAF || c + 3 < 4) ? 6 : 10);
    if (c + 2 >= NCH) {
      __syncthreads();  // last pair: full drain before epilogue reuses smem
    } else {
      __builtin_amdgcn_s_barrier();  // no drain: in-order vmcnt + B-waits
    }
  }

  // ===== epilogue: padded-tile transpose, all global I/O coalesced ========
  float* T0 = (float*)smem;  // [64][68] f32
  float* T1 = T0 + 64 * 68;
  const int rbase = erow * 68 + (eseg << 4);

  float cred[16];
  if constexpr (!LEAF) {
    float c0v[16], c1v[16];
#pragma unroll
    for (int j = 0; j < 8; ++j) {
      c0v[j] = (float)cpa0[j]; c0v[8 + j] = (float)cpa1[j];
      c1v[j] = (float)cpb0[j]; c1v[8 + j] = (float)cpb1[j];
    }
#pragma unroll
    for (int rf = 0; rf < 4; ++rf)
#pragma unroll
      for (int rr = 0; rr < 4; ++rr) {
        const int prow = rf * 16 + (q << 2) + rr;
        T0[prow * 68 + scol] = sigP(acc[3][rf][rr] + bf0);
        T1[prow * 68 + scol] = sigP(acc[4][rf][rr] + bf1);
      }
    __syncthreads();
#pragma unroll
    for (int jj = 0; jj < 4; ++jj) {
      float4 f04 = *(const float4*)&T0[rbase + jj * 4];
      float4 f14 = *(const float4*)&T1[rbase + jj * 4];
      cred[jj * 4 + 0] = f04.x * c0v[jj * 4 + 0] + f14.x * c1v[jj * 4 + 0];
      cred[jj * 4 + 1] = f04.y * c0v[jj * 4 + 1] + f14.y * c1v[jj * 4 + 1];
      cred[jj * 4 + 2] = f04.z * c0v[jj * 4 + 2] + f14.z * c1v[jj * 4 + 2];
      cred[jj * 4 + 3] = f04.w * c0v[jj * 4 + 3] + f14.w * c1v[jj * 4 + 3];
    }
    __syncthreads();
  } else {
#pragma unroll
    for (int jj = 0; jj < 4; ++jj) {
      cred[jj * 4 + 0] = cpre[jj].x; cred[jj * 4 + 1] = cpre[jj].y;
      cred[jj * 4 + 2] = cpre[jj].z; cred[jj * 4 + 3] = cpre[jj].w;
    }
  }

  {
#pragma unroll
    for (int rf = 0; rf < 4; ++rf)
#pragma unroll
      for (int rr = 0; rr < 4; ++rr) {
        const int prow = rf * 16 + (q << 2) + rr;
        const float iv = sigP(acc[0][rf][rr] + bi);
        const float uv = tanhP(acc[2][rf][rr] + bu);
        const float ov = sigP(acc[1][rf][rr] + bo);
        T0[prow * 68 + scol] = iv * uv;
        T1[prow * 68 + scol] = ov;
      }
  }
  __syncthreads();

  if (pv) {
    float4 h4[4], c4[4];
#pragma unroll
    for (int jj = 0; jj < 4; ++jj) {
      float4 iu4 = *(const float4*)&T0[rbase + jj * 4];
      float4 o4 = *(const float4*)&T1[rbase + jj * 4];
      float cc;
      cc = iu4.x + cred[jj * 4 + 0]; c4[jj].x = cc; h4[jj].x = o4.x * tanhP(cc);
      cc = iu4.y + cred[jj * 4 + 1]; c4[jj].y = cc; h4[jj].y = o4.y * tanhP(cc);
      cc = iu4.z + cred[jj * 4 + 2]; c4[jj].z = cc; h4[jj].z = o4.z * tanhP(cc);
      cc = iu4.w + cred[jj * 4 + 3]; c4[jj].w = cc; h4[jj].w = o4.w * tanhP(cc);
    }
    const size_t ob = (size_t)(off + p_e) * 256 + (nb << 6) + (eseg << 4);
    float* dst = out + ob;
#pragma unroll
    for (int jj = 0; jj < 4; ++jj) *(float4*)(dst + jj * 4) = h4[jj];
    *(f16x8*)(hws + ob) = pack8(h4[0], h4[1]);
    *(f16x8*)(hws + ob + 8) = pack8(h4[2], h4[3]);
    *(f16x8*)(cws + ob) = pack8(c4[0], c4[1]);
    *(f16x8*)(cws + ob + 8) = pack8(c4[2], c4[3]);
  }
}

// ==================== R12 fallback (no x16 workspace) ======================
template <bool LEAF, bool H16, typename CT>
__global__ __launch_bounds__(256, 2) void level_kernel(
    const float* __restrict__ x, const float* __restrict__ c0in,
    const _Float16* __restrict__ Wb2, const float* __restrict__ b_iou,
    const float* __restrict__ U_f_b, float* __restrict__ out,
    CT* __restrict__ cws, _Float16* __restrict__ hws, int m, int off,
    int coff) {
  constexpr int NG = LEAF ? 3 : 5;
  constexpr int NCH = LEAF ? 4 : 12;
  constexpr int NBU = NG * 2;
  __shared__ __align__(16) char smem[34816];
  f16x8* sA = (f16x8*)smem;

  const int tid = threadIdx.x;
  const int w = tid >> 6;
  const int lane = tid & 63;
  const int l15 = lane & 15;
  const int q = lane >> 4;
  int bx = blockIdx.x, r, nb;
  if ((gridDim.x & 31) == 0) {
    nb = (bx >> 3) & 3;
    r = ((bx >> 5) << 3) + (bx & 7);
  } else {
    r = bx >> 2;
    nb = bx & 3;
  }
  const int pbase = r << 6;
  const int arow = tid >> 3;
  const int akc = tid & 7;

  const _Float16* bb =
      Wb2 + (size_t)(nb * 4 + w) * (5 * 24 * 512) + l15 * 32 + q * 8;

  f32x4 acc[NG][4] = {};

  auto LOADA = [&](float4 (&ax)[2][2], f16x8 (&ah)[2], int c) {
    const int k0 = (c << 6) + (akc << 3);
#pragma unroll
    for (int j = 0; j < 2; ++j) {
      const int row = arow + j * 32;
      const int p = pbase + row;
      const bool xpart = LEAF || c < 4;
      if (p < m) {
        if (xpart) {
          const float* src = x + (size_t)(off + p) * 256 + k0;
          ax[j][0] = *(const float4*)src;
          ax[j][1] = *(const float4*)(src + 4);
        } else if (H16) {
          ah[j] = *(const f16x8*)(hws + (size_t)(coff + 2 * p) * 256 +
                                  (k0 - 256));
        } else {
          const float* src = out + (size_t)(coff + 2 * p) * 256 + (k0 - 256);
          ax[j][0] = *(const float4*)src;
          ax[j][1] = *(const float4*)(src + 4);
        }
      } else {
        ax[j][0] = float4{0.f, 0.f, 0.f, 0.f};
        ax[j][1] = float4{0.f, 0.f, 0.f, 0.f};
        f16x8 z = {};
        ah[j] = z;
      }
    }
  };
  auto WRITEA = [&](float4 (&ax)[2][2], f16x8 (&ah)[2], int c) {
#pragma unroll
    for (int j = 0; j < 2; ++j) {
      const int row = arow + j * 32;
      f16x8 v;
      if (H16 && !LEAF && c >= 4) v = ah[j];
      else v = pack8(ax[j][0], ax[j][1]);
      sA[((c & 1) << 9) | (row << 3) | (akc ^ (row & 7))] = v;
    }
  };
  auto LOADB = [&](f16x8 (&bv)[NBU], int c) {
#pragma unroll
    for (int j = 0; j < NBU; ++j)
      bv[j] = *(const f16x8*)(bb + (((j >> 1) * 24 + c * 2 + (j & 1)) << 9));
  };
  auto COMPUTE = [&](int buf, f16x8 (&bv)[NBU]) {
#pragma unroll
    for (int ks = 0; ks < 2; ++ks) {
      f16x8 af[4];
#pragma unroll
      for (int rf = 0; rf < 4; ++rf) {
        const int row = rf * 16 + l15;
        af[rf] = sA[(buf << 9) | (row << 3) | ((ks * 4 + q) ^ (row & 7))];
      }
#pragma unroll
      for (int g = 0; g < NG; ++g) {
        const f16x8 bf = bv[g * 2 + ks];
#pragma unroll
        for (int rf = 0; rf < 4; ++rf)
          acc[g][rf] = __builtin_amdgcn_mfma_f32_16x16x32_f16(
              af[rf], bf, acc[g][rf], 0, 0, 0);
      }
    }
  };

  float4 axA[2][2], axB[2][2];
  f16x8 ahA[2], ahB[2];
  f16x8 bvA[NBU], bvB[NBU];

  LOADA(axA, ahA, 0);
  LOADB(bvA, 0);
  WRITEA(axA, ahA, 0);
  LOADA(axB, ahB, 1);
  LOADB(bvB, 1);
  __syncthreads();

  for (int c = 0; c < NCH; c += 2) {
    if (c + 2 < NCH) LOADA(axA, ahA, c + 2);
    COMPUTE(0, bvA);
    WRITEA(axB, ahB, c + 1);
    if (c + 2 < NCH) LOADB(bvA, c + 2);
    __syncthreads();
    if (c + 3 < NCH) LOADA(axB, ahB, c + 3);
    COMPUTE(1, bvB);
    if (c + 2 < NCH) {
      WRITEA(axA, ahA, c + 2);
      if (c + 3 < NCH) LOADB(bvB, c + 3);
      __syncthreads();
    }
  }
  __syncthreads();

  const int erow = tid >> 2;
  const int eseg = tid & 3;
  const int p_e = pbase + erow;
  const bool pv = p_e < m;
  float* T0 = (float*)smem;
  float* T1 = T0 + 64 * 68;
  const int scol = (w << 4) + l15;
  const int n = (nb << 6) + scol;
  const int rbase = erow * 68 + (eseg << 4);

  float cred[16];
  if constexpr (!LEAF) {
    float c0v[16], c1v[16];
    if (pv) {
      const CT* csrc =
          cws + (size_t)(coff + 2 * p_e) * 256 + (nb << 6) + (eseg << 4);
      if constexpr (sizeof(CT) == 2) {
        f16x8 a0 = *(const f16x8*)csrc;
        f16x8 a1 = *(const f16x8*)(csrc + 8);
        f16x8 b0 = *(const f16x8*)(csrc + 256);
        f16x8 b1 = *(const f16x8*)(csrc + 264);
#pragma unroll
        for (int j = 0; j < 8; ++j) {
          c0v[j] = (float)a0[j]; c0v[8 + j] = (float)a1[j];
          c1v[j] = (float)b0[j]; c1v[8 + j] = (float)b1[j];
        }
      } else {
#pragma unroll
        for (int jj = 0; jj < 4; ++jj) {
          float4 v0 = *(const float4*)((const float*)csrc + jj * 4);
          float4 v1 = *(const float4*)((const float*)csrc + 256 + jj * 4);
          c0v[jj * 4 + 0] = v0.x; c0v[jj * 4 + 1] = v0.y;
          c0v[jj * 4 + 2] = v0.z; c0v[jj * 4 + 3] = v0.w;
          c1v[jj * 4 + 0] = v1.x; c1v[jj * 4 + 1] = v1.y;
          c1v[jj * 4 + 2] = v1.z; c1v[jj * 4 + 3] = v1.w;
        }
      }
    } else {
#pragma unroll
      for (int j = 0; j < 16; ++j) { c0v[j] = 0.f; c1v[j] = 0.f; }
    }
    const float bf0 = U_f_b[n], bf1 = U_f_b[256 + n];
#pragma unroll
    for (int rf = 0; rf < 4; ++rf)
#pragma unroll
      for (int rr = 0; rr < 4; ++rr) {
        const int prow = rf * 16 + (q << 2) + rr;
        T0[prow * 68 + scol] = sigP(acc[3][rf][rr] + bf0);
        T1[prow * 68 + scol] = sigP(acc[4][rf][rr] + bf1);
      }
    __syncthreads();
#pragma unroll
    for (int jj = 0; jj < 4; ++jj) {
      float4 f04 = *(const float4*)&T0[rbase + jj * 4];
      float4 f14 = *(const float4*)&T1[rbase + jj * 4];
      cred[jj * 4 + 0] = f04.x * c0v[jj * 4 + 0] + f14.x * c1v[jj * 4 + 0];
      cred[jj * 4 + 1] = f04.y * c0v[jj * 4 + 1] + f14.y * c1v[jj * 4 + 1];
      cred[jj * 4 + 2] = f04.z * c0v[jj * 4 + 2] + f14.z * c1v[jj * 4 + 2];
      cred[jj * 4 + 3] = f04.w * c0v[jj * 4 + 3] + f14.w * c1v[jj * 4 + 3];
    }
    __syncthreads();
  } else {
    if (pv) {
      const float* src =
          c0in + (size_t)(off + p_e) * 256 + (nb << 6) + (eseg << 4);
#pragma unroll
      for (int jj = 0; jj < 4; ++jj) {
        float4 v = *(const float4*)(src + jj * 4);
        cred[jj * 4 + 0] = v.x; cred[jj * 4 + 1] = v.y;
        cred[jj * 4 + 2] = v.z; cred[jj * 4 + 3] = v.w;
      }
    } else {
#pragma unroll
      for (int j = 0; j < 16; ++j) cred[j] = 0.f;
    }
  }

  {
    const float bi = b_iou[n], bo = b_iou[256 + n], bu = b_iou[512 + n];
#pragma unroll
    for (int rf = 0; rf < 4; ++rf)
#pragma unroll
      for (int rr = 0; rr < 4; ++rr) {
        const int prow = rf * 16 + (q << 2) + rr;
        const float iv = sigP(acc[0][rf][rr] + bi);
        const float uv = tanhP(acc[2][rf][rr] + bu);
        const float ov = sigP(acc[1][rf][rr] + bo);
        T0[prow * 68 + scol] = iv * uv;
        T1[prow * 68 + scol] = ov;
      }
  }
  __syncthreads();

  if (pv) {
    float4 h4[4], c4[4];
#pragma unroll
    for (int jj = 0; jj < 4; ++jj) {
      float4 iu4 = *(const float4*)&T0[rbase + jj * 4];
      float4 o4 = *(const float4*)&T1[rbase + jj * 4];
      float cc;
      cc = iu4.x + cred[jj * 4 + 0]; c4[jj].x = cc; h4[jj].x = o4.x * tanhP(cc);
      cc = iu4.y + cred[jj * 4 + 1]; c4[jj].y = cc; h4[jj].y = o4.y * tanhP(cc);
      cc = iu4.z + cred[jj * 4 + 2]; c4[jj].z = cc; h4[jj].z = o4.z * tanhP(cc);
      cc = iu4.w + cred[jj * 4 + 3]; c4[jj].w = cc; h4[jj].w = o4.w * tanhP(cc);
    }
    const size_t ob = (size_t)(off + p_e) * 256 + (nb << 6) + (eseg << 4);
    float* dst = out + ob;
#pragma unroll
    for (int jj = 0; jj < 4; ++jj) *(float4*)(dst + jj * 4) = h4[jj];
    if constexpr (H16) {
      *(f16x8*)(hws + ob) = pack8(h4[0], h4[1]);
      *(f16x8*)(hws + ob + 8) = pack8(h4[2], h4[3]);
    }
    if constexpr (sizeof(CT) == 2) {
      *(f16x8*)((_Float16*)cws + ob) = pack8(c4[0], c4[1]);
      *(f16x8*)((_Float16*)cws + ob + 8) = pack8(c4[2], c4[3]);
    } else {
      float* cdst = (float*)cws + ob;
#pragma unroll
      for (int jj = 0; jj < 4; ++jj) *(float4*)(cdst + jj * 4) = c4[jj];
    }
  }
}

template <bool H16, typename CT>
static void run_levels(const float* x, const float* c0, const _Float16* Wb2,
                       const float* b_iou, const float* U_f_b, float* out,
                       CT* cws, _Float16* hws, hipStream_t stream) {
  level_kernel<true, H16, CT><<<dim3(4096), 256, 0, stream>>>(
      x, c0, Wb2, b_iou, U_f_b, out, cws, hws, 65536, 65535, 0);
  for (int k = DEPTH - 2; k >= 0; --k) {
    const int m = 1 << k;
    const int R = (m + 63) / 64;
    level_kernel<false, H16, CT><<<dim3(R * 4), 256, 0, stream>>>(
        x, c0, Wb2, b_iou, U_f_b, out, cws, hws, m, m - 1, 2 * m - 1);
  }
}

extern "C" void kernel_launch(void* const* d_in, const int* in_sizes, int n_in,
                              void* d_out, int out_size, void* d_ws, size_t ws_size,
                              hipStream_t stream) {
  const float* x     = (const float*)d_in[0];
  // d_in[1] = h0 (unused by the reference's math)
  const float* c0    = (const float*)d_in[2];
  const float* W_iou = (const float*)d_in[3];
  const float* U_iou = (const float*)d_in[4];
  const float* b_iou = (const float*)d_in[5];
  const float* U_f_w = (const float*)d_in[6];
  const float* U_f_b = (const float*)d_in[7];
  float* out = (float*)d_out;

  char* ws = (char*)d_ws;
  const size_t wbBytes = (size_t)1280 * 768 * 2;  // 1.97 MB, 16B-aligned
  _Float16* Wb2 = (_Float16*)ws;
  build_wb2<<<3840, 256, 0, stream>>>(Wb2, W_iou, U_iou, U_f_w);

  const size_t cElems = (size_t)NNODES * 256;  // 33.55M
  char* p1 = ws + wbBytes;
  if (ws_size >= wbBytes + cElems * 2 * 3) {
    // tiers: [c16][h16][x16]
    _Float16* cws = (_Float16*)p1;
    _Float16* hws = (_Float16*)(p1 + cElems * 2);
    _Float16* x16 = (_Float16*)(p1 + cElems * 4);
    const int n8 = (int)(cElems / 8);
    conv_x16<<<dim3((n8 + 255) / 256), 256, 0, stream>>>(x16, x, n8);
    level16_kernel<true><<<dim3(4096), 256, 0, stream>>>(
        x16, c0, Wb2, b_iou, U_f_b, out, cws, hws, 65536, 65535, 0);
    for (int k = DEPTH - 2; k >= 0; --k) {
      const int m = 1 << k;
      const int R = (m + 63) / 64;
      level16_kernel<false><<<dim3(R * 4), 256, 0, stream>>>(
          x16, c0, Wb2, b_iou, U_f_b, out, cws, hws, m, m - 1, 2 * m - 1);
    }
  } else if (ws_size >= wbBytes + cElems * 2 + cElems * 2) {
    run_levels<true, _Float16>(x, c0, Wb2, b_iou, U_f_b, out, (_Float16*)p1,
                               (_Float16*)(p1 + cElems * 2), stream);
  } else if (ws_size >= wbBytes + cElems * 4) {
    run_levels<false, float>(x, c0, Wb2, b_iou, U_f_b, out, (float*)p1,
                             nullptr, stream);
  } else {
    run_levels<false, _Float16>(x, c0, Wb2, b_iou, U_f_b, out, (_Float16*)p1,
                                nullptr, stream);
  }
}